// Round 5
// baseline (323.258 us; speedup 1.0000x reference)
//
#include <hip/hip_runtime.h>
#include <math.h>

// Problem constants
constexpr int C_ = 128, A_ = 64, K_ = 24, S_ = 4;
constexpr int NATOM = C_ * A_;    // 8192
constexpr int FAEV = 384;         // 64 radial + 320 angular
constexpr float RCR = 5.2f, RCA = 3.5f;
constexpr float PI_F = 3.14159265358979323846f;
// exp folded to exp2: exp(-eta*x^2) = exp2(K * x^2)
constexpr float K_A2 = -8.0f  * 1.44269504f;          // angular, on (hs - shfa)^2
constexpr float K_R2 = -64.0f * 1.44269504f;          // radial, on (d/2 - shfr/2)^2  (16*4)
constexpr float SQRT095 = 0.974679434f;               // sqrt(0.95) folded into unit vectors
constexpr float SQRT2   = 1.41421356237f;             // folded into fca (gives the 2* factor)

// ---------------- kernel A: AEV + per-molecule species lists + out zero ----------------
// 4 atoms per block (one full wave per atom), grid = NATOM/4 = 2048
__global__ __launch_bounds__(256) void aev_kernel(const int* __restrict__ element_idxs,
                                                  const int* __restrict__ neighbor_idxs,
                                                  const float* __restrict__ distances,
                                                  const float* __restrict__ diff_vectors,
                                                  float* __restrict__ aev_out,
                                                  int* __restrict__ mol_cnt,
                                                  int* __restrict__ mol_lst,
                                                  float* __restrict__ out) {
    const int blk = blockIdx.x;
    const int c   = blk >> 4;            // 16 blocks per molecule
    const int t   = threadIdx.x;

    __shared__ int    elem_s[A_];
    __shared__ float4 u4_s[4][K_];       // {ux*s, uy*s, uz*s, d/2}  (s = sqrt(0.95)/d)
    __shared__ float  fcr_s[4][K_];
    __shared__ float  fca_s[4][K_];      // premultiplied by sqrt(2)
    __shared__ int    spec_s[4][K_];
    __shared__ int    bidx_s[4][S_][K_];
    __shared__ int    nsp_s[4][S_];

    if (t < A_) elem_s[t] = element_idxs[c * A_ + t];
    __syncthreads();

    // molecule-owner duties: build per-molecule species lists + zero out[c]
    if ((blk & 15) == 0) {
        if (t < S_) {
            int n = 0;
            int* lst = mol_lst + (c * S_ + t) * A_;
            for (int a = 0; a < A_; ++a)
                if (elem_s[a] == t) lst[n++] = a;
            mol_cnt[c * S_ + t] = n;
        } else if (t == S_) {
            out[c] = 0.0f;
        }
    }

    // load + precompute neighbor data (96 threads: 4 atoms x 24 nbrs)
    if (t < 4 * K_) {
        int m = t / K_, k = t - m * K_;
        int base = (blk * 4 + m) * K_ + k;
        int nb = neighbor_idxs[base];
        float d = distances[base];
        float inv = __builtin_amdgcn_rcpf(d) * SQRT095;
        float4 u;
        u.x = diff_vectors[base * 3 + 0] * inv;
        u.y = diff_vectors[base * 3 + 1] * inv;
        u.z = diff_vectors[base * 3 + 2] * inv;
        u.w = 0.5f * d;
        u4_s[m][k] = u;
        spec_s[m][k] = elem_s[nb];
        fcr_s[m][k] = (d < RCR) ? (0.5f * __cosf(PI_F * d * (1.0f / RCR)) + 0.5f) : 0.0f;
        fca_s[m][k] = (d < RCA) ? (SQRT2 * (0.5f * __cosf(PI_F * d * (1.0f / RCA)) + 0.5f)) : 0.0f;
    }
    __syncthreads();

    // bucket active neighbors by species (16 threads)
    if (t < 4 * S_) {
        int m = t >> 2, sp = t & 3, n = 0;
        #pragma unroll
        for (int k = 0; k < K_; ++k)
            if (fca_s[m][k] > 0.0f && spec_s[m][k] == sp) bidx_s[m][sp][n++] = k;
        nsp_s[m][sp] = n;
    }
    __syncthreads();

    // ---- per-atom phase: FULL wave per atom ----
    const int m      = t >> 6;           // 0..3
    const int lane   = t & 63;
    const int lane32 = lane & 31;
    const int par    = lane >> 5;        // pair-parity: low half = even pairs, high = odd
    float* aev = aev_out + (size_t)(blk * 4 + m) * FAEV;

    // radial: lane = sp*16 + shell  (64 features exactly)
    {
        const int   spg   = lane >> 4;
        const float shfrh = 0.5f * (0.9f + 0.26875f * (float)(lane & 15));
        float acc = 0.0f;
        #pragma unroll
        for (int k = 0; k < K_; ++k) {
            float hd = u4_s[m][k].w;
            float df = hd - shfrh;
            float term = 0.25f * exp2f(df * df * K_R2) * fcr_s[m][k];
            if (spec_s[m][k] == spg) acc += term;
        }
        aev[lane] = acc;
    }

    // angular: 10 species-pair segments; both wave halves = same atom, even/odd pairs
    const int zz = lane32 >> 2, yy = lane32 & 3;
    const float cz2 = 0.5f * __cosf(((float)zz + 0.5f) * (PI_F / 8.0f));
    const float sz2 = 0.5f * __sinf(((float)zz + 0.5f) * (PI_F / 8.0f));
    const float shfa_l = 0.9f + 0.65f * (float)yy;

    auto pair_term = [&](int j, int k2) -> float {
        float4 u1 = u4_s[m][j], u2 = u4_s[m][k2];
        float ca = u1.x * u2.x + u1.y * u2.y + u1.z * u2.z;   // = 0.95*cos
        float sa = sqrtf(1.0f - ca * ca);                     // ca^2 <= 0.9025, safe
        float dd = (u1.w + u2.w) - shfa_l;                    // (d1+d2)/2 - shfa
        float f2 = exp2f(dd * dd * K_A2);
        float x  = 0.5f + ca * cz2 + sa * sz2;
        float x2 = x * x, x4 = x2 * x2, x8 = x4 * x4, x16 = x8 * x8;
        float tc = fca_s[m][j] * fca_s[m][k2];                // = 2*fc1*fc2
        return (x16 * x16) * (f2 * tc);
    };

    #pragma unroll
    for (int spa = 0; spa < 4; ++spa) {
        #pragma unroll
        for (int spb = spa; spb < 4; ++spb) {
            const int pidx = spa * (9 - spa) / 2 + (spb - spa);
            const int na  = nsp_s[m][spa];
            const int nb2 = nsp_s[m][spb];
            float acc = 0.0f;
            if (spa == spb) {
                // triangular pair stream (jj<kk), stride 2 starting at parity
                int jj = 0, kk = 1 + par;
                while (jj < na - 1 && kk >= na) { int ov = kk - na; ++jj; kk = jj + 1 + ov; }
                while (jj < na - 1) {
                    acc += pair_term(bidx_s[m][spa][jj], bidx_s[m][spa][kk]);
                    kk += 2;
                    while (jj < na - 1 && kk >= na) { int ov = kk - na; ++jj; kk = jj + 1 + ov; }
                }
            } else {
                // rectangular pair stream
                int jj = 0, kk = par;
                while (jj < na && kk >= nb2) { kk -= nb2; ++jj; }
                while (jj < na) {
                    acc += pair_term(bidx_s[m][spa][jj], bidx_s[m][spb][kk]);
                    kk += 2;
                    while (jj < na && kk >= nb2) { kk -= nb2; ++jj; }
                }
            }
            float other = __shfl(acc, lane32 + 32);           // add the other half's partial
            if (lane < 32) aev[64 + pidx * 32 + lane32] = acc + other;
        }
    }
}

// ---------------- kernel B: MLP, 16 atoms of one (molecule, species) per block ----------------
// grid = C*S*4 tiles = 2048
__global__ __launch_bounds__(256) void mlp_kernel(const float* __restrict__ aev_ws,
                                                  const int* __restrict__ mol_cnt,
                                                  const int* __restrict__ mol_lst,
                                                  const float* __restrict__ W1, const float* __restrict__ b1,
                                                  const float* __restrict__ W2, const float* __restrict__ b2,
                                                  const float* __restrict__ W3, const float* __restrict__ b3,
                                                  const float* __restrict__ W4, const float* __restrict__ b4,
                                                  float* __restrict__ out) {
    const int blk  = blockIdx.x;
    const int tile = blk & 3;
    const int s    = (blk >> 2) & 3;
    const int c    = blk >> 4;
    const int cnt  = mol_cnt[c * S_ + s];
    const int base = tile * 16;
    if (base >= cnt) return;
    const int matoms = min(16, cnt - base);
    const int t = threadIdx.x;

    __shared__ float aev_s[16][FAEV];    // overlaid by h2 (16x128) + h3 (16x96) after layer 1
    __shared__ float h1_s[16][160];
    float (*h2_s)[128] = (float(*)[128])&aev_s[0][0];
    float (*h3_s)[96]  = (float(*)[96])(&aev_s[0][0] + 16 * 128);

    // load tile: 16 threads per row, 6 float4 each
    {
        int m = t >> 4, l = t & 15;
        float4* dst = (float4*)&aev_s[m][0];
        if (m < matoms) {
            int a = mol_lst[(c * S_ + s) * A_ + base + m];
            const float4* src = (const float4*)(aev_ws + (size_t)(c * A_ + a) * FAEV);
            #pragma unroll
            for (int i = 0; i < 6; ++i) dst[l + 16 * i] = src[l + 16 * i];
        } else {
            #pragma unroll
            for (int i = 0; i < 6; ++i) dst[l + 16 * i] = make_float4(0.f, 0.f, 0.f, 0.f);
        }
    }
    __syncthreads();

    const float* W1s = W1 + s * (FAEV * 160);
    const float* b1s = b1 + s * 160;
    const float* W2s = W2 + s * (160 * 128);
    const float* b2s = b2 + s * 128;
    const float* W3s = W3 + s * (128 * 96);
    const float* b3s = b3 + s * 96;
    const float* W4s = W4 + s * 96;
    const float* b4s = b4 + s;

    // ---- layer 1: 384 -> 160 ----
    if (t < 160) {
        float acc[16];
        #pragma unroll
        for (int m = 0; m < 16; ++m) acc[m] = 0.0f;
        for (int f = 0; f < FAEV; f += 4) {
            float w0 = W1s[(f + 0) * 160 + t];
            float w1 = W1s[(f + 1) * 160 + t];
            float w2 = W1s[(f + 2) * 160 + t];
            float w3 = W1s[(f + 3) * 160 + t];
            #pragma unroll
            for (int m = 0; m < 16; ++m) {
                float4 av = *(const float4*)&aev_s[m][f];   // broadcast read
                acc[m] += av.x * w0 + av.y * w1 + av.z * w2 + av.w * w3;
            }
        }
        float bb = b1s[t];
        #pragma unroll
        for (int m = 0; m < 16; ++m) {
            float x = acc[m] + bb;
            h1_s[m][t] = (x > 0.0f) ? x : 0.1f * (__expf(10.0f * x) - 1.0f);
        }
    }
    __syncthreads();   // aev_s dead -> reuse as h2/h3

    // ---- layer 2: 160 -> 128 ----
    if (t < 128) {
        float acc[16];
        #pragma unroll
        for (int m = 0; m < 16; ++m) acc[m] = 0.0f;
        for (int f = 0; f < 160; f += 4) {
            float w0 = W2s[(f + 0) * 128 + t];
            float w1 = W2s[(f + 1) * 128 + t];
            float w2 = W2s[(f + 2) * 128 + t];
            float w3 = W2s[(f + 3) * 128 + t];
            #pragma unroll
            for (int m = 0; m < 16; ++m) {
                float4 av = *(const float4*)&h1_s[m][f];
                acc[m] += av.x * w0 + av.y * w1 + av.z * w2 + av.w * w3;
            }
        }
        float bb = b2s[t];
        #pragma unroll
        for (int m = 0; m < 16; ++m) {
            float x = acc[m] + bb;
            h2_s[m][t] = (x > 0.0f) ? x : 0.1f * (__expf(10.0f * x) - 1.0f);
        }
    }
    __syncthreads();

    // ---- layer 3: 128 -> 96 ----
    if (t < 96) {
        float acc[16];
        #pragma unroll
        for (int m = 0; m < 16; ++m) acc[m] = 0.0f;
        for (int f = 0; f < 128; f += 4) {
            float w0 = W3s[(f + 0) * 96 + t];
            float w1 = W3s[(f + 1) * 96 + t];
            float w2 = W3s[(f + 2) * 96 + t];
            float w3 = W3s[(f + 3) * 96 + t];
            #pragma unroll
            for (int m = 0; m < 16; ++m) {
                float4 av = *(const float4*)&h2_s[m][f];
                acc[m] += av.x * w0 + av.y * w1 + av.z * w2 + av.w * w3;
            }
        }
        float bb = b3s[t];
        #pragma unroll
        for (int m = 0; m < 16; ++m) {
            float x = acc[m] + bb;
            h3_s[m][t] = (x > 0.0f) ? x : 0.1f * (__expf(10.0f * x) - 1.0f);
        }
    }
    __syncthreads();

    // ---- layer 4: 96 -> 1, accumulate per molecule ----
    if (t < matoms) {
        float e = b4s[0];
        for (int f = 0; f < 96; ++f) e += h3_s[t][f] * W4s[f];
        atomicAdd(&out[c], e);
    }
}

extern "C" void kernel_launch(void* const* d_in, const int* in_sizes, int n_in,
                              void* d_out, int out_size, void* d_ws, size_t ws_size,
                              hipStream_t stream) {
    const int*   element_idxs  = (const int*)d_in[0];
    const int*   neighbor_idxs = (const int*)d_in[1];
    const float* distances     = (const float*)d_in[2];
    const float* diff_vectors  = (const float*)d_in[3];
    const float* W1 = (const float*)d_in[4];
    const float* b1 = (const float*)d_in[5];
    const float* W2 = (const float*)d_in[6];
    const float* b2 = (const float*)d_in[7];
    const float* W3 = (const float*)d_in[8];
    const float* b3 = (const float*)d_in[9];
    const float* W4 = (const float*)d_in[10];
    const float* b4 = (const float*)d_in[11];
    float* out = (float*)d_out;

    // workspace layout
    float* aev_ws  = (float*)d_ws;                                       // 8192*384 f32 = 12.58 MB
    int*   mol_cnt = (int*)((char*)d_ws + (size_t)NATOM * FAEV * 4);     // 128*4 ints
    int*   mol_lst = mol_cnt + C_ * S_;                                  // 128*4*64 ints

    hipLaunchKernelGGL(aev_kernel, dim3(NATOM / 4), dim3(256), 0, stream,
                       element_idxs, neighbor_idxs, distances, diff_vectors,
                       aev_ws, mol_cnt, mol_lst, out);
    hipLaunchKernelGGL(mlp_kernel, dim3(C_ * S_ * 4), dim3(256), 0, stream,
                       aev_ws, mol_cnt, mol_lst,
                       W1, b1, W2, b2, W3, b3, W4, b4, out);
}

// Round 6
// 257.230 us; speedup vs baseline: 1.2567x; 1.2567x over previous
//
#include <hip/hip_runtime.h>
#include <math.h>

// Problem constants
constexpr int C_ = 128, A_ = 64, K_ = 24, S_ = 4;
constexpr int NATOM = C_ * A_;    // 8192
constexpr int FAEV = 384;         // 64 radial + 320 angular
constexpr float RCR = 5.2f, RCA = 3.5f;
constexpr float PI_F = 3.14159265358979323846f;
// exp folded to exp2: exp(-eta*x^2) = exp2(K * x^2)
constexpr float K_A2 = -8.0f  * 1.44269504f;          // angular, on (hs - shfa)^2
constexpr float K_R2 = -64.0f * 1.44269504f;          // radial, on (d/2 - shfr/2)^2  (16*4)
constexpr float SQRT095 = 0.974679434f;               // sqrt(0.95) folded into unit vectors
constexpr float SQRT2   = 1.41421356237f;             // folded into fca (gives the 2* factor)

// ---------------- kernel A: AEV + per-molecule species lists + out zero ----------------
// 4 atoms per block (one full wave per atom), grid = NATOM/4 = 2048
__global__ __launch_bounds__(256) void aev_kernel(const int* __restrict__ element_idxs,
                                                  const int* __restrict__ neighbor_idxs,
                                                  const float* __restrict__ distances,
                                                  const float* __restrict__ diff_vectors,
                                                  float* __restrict__ aev_out,
                                                  int* __restrict__ mol_cnt,
                                                  int* __restrict__ mol_lst,
                                                  float* __restrict__ out) {
    const int blk = blockIdx.x;
    const int c   = blk >> 4;            // 16 blocks per molecule
    const int t   = threadIdx.x;

    __shared__ int    elem_s[A_];
    __shared__ float4 u4_s[4][K_];       // {ux*s, uy*s, uz*s, d/2}  (s = sqrt(0.95)/d)
    __shared__ float  fcr_s[4][K_];
    __shared__ float  fca_s[4][K_];      // premultiplied by sqrt(2)
    __shared__ int    spec_s[4][K_];
    __shared__ int    bidx_s[4][S_][K_];
    __shared__ int    nsp_s[4][S_];

    if (t < A_) elem_s[t] = element_idxs[c * A_ + t];
    __syncthreads();

    // molecule-owner duties: build per-molecule species lists + zero out[c]
    if ((blk & 15) == 0) {
        if (t < S_) {
            int n = 0;
            int* lst = mol_lst + (c * S_ + t) * A_;
            for (int a = 0; a < A_; ++a)
                if (elem_s[a] == t) lst[n++] = a;
            mol_cnt[c * S_ + t] = n;
        } else if (t == S_) {
            out[c] = 0.0f;
        }
    }

    // load + precompute neighbor data (96 threads: 4 atoms x 24 nbrs)
    if (t < 4 * K_) {
        int m = t / K_, k = t - m * K_;
        int base = (blk * 4 + m) * K_ + k;
        int nb = neighbor_idxs[base];
        float d = distances[base];
        float inv = __builtin_amdgcn_rcpf(d) * SQRT095;
        float4 u;
        u.x = diff_vectors[base * 3 + 0] * inv;
        u.y = diff_vectors[base * 3 + 1] * inv;
        u.z = diff_vectors[base * 3 + 2] * inv;
        u.w = 0.5f * d;
        u4_s[m][k] = u;
        spec_s[m][k] = elem_s[nb];
        fcr_s[m][k] = (d < RCR) ? (0.5f * __cosf(PI_F * d * (1.0f / RCR)) + 0.5f) : 0.0f;
        fca_s[m][k] = (d < RCA) ? (SQRT2 * (0.5f * __cosf(PI_F * d * (1.0f / RCA)) + 0.5f)) : 0.0f;
    }
    __syncthreads();

    // bucket active neighbors by species (16 threads)
    if (t < 4 * S_) {
        int m = t >> 2, sp = t & 3, n = 0;
        #pragma unroll
        for (int k = 0; k < K_; ++k)
            if (fca_s[m][k] > 0.0f && spec_s[m][k] == sp) bidx_s[m][sp][n++] = k;
        nsp_s[m][sp] = n;
    }
    __syncthreads();

    // ---- per-atom phase: FULL wave per atom ----
    const int m      = t >> 6;           // 0..3
    const int lane   = t & 63;
    const int lane32 = lane & 31;
    const int par    = lane >> 5;        // pair-parity: low half = even pairs, high = odd
    float* aev = aev_out + (size_t)(blk * 4 + m) * FAEV;

    // radial: lane = sp*16 + shell  (64 features exactly)
    {
        const int   spg   = lane >> 4;
        const float shfrh = 0.5f * (0.9f + 0.26875f * (float)(lane & 15));
        float acc = 0.0f;
        #pragma unroll
        for (int k = 0; k < K_; ++k) {
            float hd = u4_s[m][k].w;
            float df = hd - shfrh;
            float term = 0.25f * exp2f(df * df * K_R2) * fcr_s[m][k];
            if (spec_s[m][k] == spg) acc += term;
        }
        aev[lane] = acc;
    }

    // angular: 10 species-pair segments; both wave halves = same atom, even/odd pairs
    const int zz = lane32 >> 2, yy = lane32 & 3;
    const float cz2 = 0.5f * __cosf(((float)zz + 0.5f) * (PI_F / 8.0f));
    const float sz2 = 0.5f * __sinf(((float)zz + 0.5f) * (PI_F / 8.0f));
    const float shfa_l = 0.9f + 0.65f * (float)yy;

    auto pair_term = [&](int j, int k2) -> float {
        float4 u1 = u4_s[m][j], u2 = u4_s[m][k2];
        float ca = u1.x * u2.x + u1.y * u2.y + u1.z * u2.z;   // = 0.95*cos
        float sa = sqrtf(1.0f - ca * ca);                     // ca^2 <= 0.9025, safe
        float dd = (u1.w + u2.w) - shfa_l;                    // (d1+d2)/2 - shfa
        float f2 = exp2f(dd * dd * K_A2);
        float x  = 0.5f + ca * cz2 + sa * sz2;
        float x2 = x * x, x4 = x2 * x2, x8 = x4 * x4, x16 = x8 * x8;
        float tc = fca_s[m][j] * fca_s[m][k2];                // = 2*fc1*fc2
        return (x16 * x16) * (f2 * tc);
    };

    #pragma unroll
    for (int spa = 0; spa < 4; ++spa) {
        #pragma unroll
        for (int spb = spa; spb < 4; ++spb) {
            const int pidx = spa * (9 - spa) / 2 + (spb - spa);
            const int na  = nsp_s[m][spa];
            const int nb2 = nsp_s[m][spb];
            float acc = 0.0f;
            if (spa == spb) {
                // triangular pair stream (jj<kk), stride 2 starting at parity
                int jj = 0, kk = 1 + par;
                while (jj < na - 1 && kk >= na) { int ov = kk - na; ++jj; kk = jj + 1 + ov; }
                while (jj < na - 1) {
                    acc += pair_term(bidx_s[m][spa][jj], bidx_s[m][spa][kk]);
                    kk += 2;
                    while (jj < na - 1 && kk >= na) { int ov = kk - na; ++jj; kk = jj + 1 + ov; }
                }
            } else {
                // rectangular pair stream
                int jj = 0, kk = par;
                while (jj < na && kk >= nb2) { kk -= nb2; ++jj; }
                while (jj < na) {
                    acc += pair_term(bidx_s[m][spa][jj], bidx_s[m][spb][kk]);
                    kk += 2;
                    while (jj < na && kk >= nb2) { kk -= nb2; ++jj; }
                }
            }
            float other = __shfl(acc, lane32 + 32);           // add the other half's partial
            if (lane < 32) aev[64 + pidx * 32 + lane32] = acc + other;
        }
    }
}

// ---------------- kernel B: MLP, 4 atoms of one (molecule, species) per block ----------------
// grid = C*S*6 = 3072 blocks; stride-6 tile loop covers any species count
__global__ __launch_bounds__(256) void mlp_kernel(const float* __restrict__ aev_ws,
                                                  const int* __restrict__ mol_cnt,
                                                  const int* __restrict__ mol_lst,
                                                  const float* __restrict__ W1, const float* __restrict__ b1,
                                                  const float* __restrict__ W2, const float* __restrict__ b2,
                                                  const float* __restrict__ W3, const float* __restrict__ b3,
                                                  const float* __restrict__ W4, const float* __restrict__ b4,
                                                  float* __restrict__ out) {
    const int blk   = blockIdx.x;
    const int cell  = blk / 6;           // 0..511 : (molecule, species)
    const int tile0 = blk - cell * 6;
    const int c     = cell >> 2;
    const int s     = cell & 3;
    const int cnt   = mol_cnt[c * S_ + s];
    const int t     = threadIdx.x;

    __shared__ float aev_s[4][FAEV];     // overlaid by h2 (4x128) + h3 (4x96) after layer 1
    __shared__ float h1_s[4][160];
    float (*h2_s)[128] = (float(*)[128])&aev_s[0][0];
    float (*h3_s)[96]  = (float(*)[96])(&aev_s[0][0] + 4 * 128);

    const float* W1s = W1 + s * (FAEV * 160);
    const float* b1s = b1 + s * 160;
    const float* W2s = W2 + s * (160 * 128);
    const float* b2s = b2 + s * 128;
    const float* W3s = W3 + s * (128 * 96);
    const float* b3s = b3 + s * 96;
    const float* W4s = W4 + s * 96;
    const float  bb4 = b4[s];

    for (int tile = tile0; tile * 4 < cnt; tile += 6) {
        const int base   = tile * 4;
        const int matoms = min(4, cnt - base);

        // ---- load tile: 4 rows x 64 lanes; row = 96 float4 ----
        {
            int m = t >> 6, l = t & 63;
            float4* dst = (float4*)&aev_s[m][0];
            if (m < matoms) {
                int a = mol_lst[(c * S_ + s) * A_ + base + m];
                const float4* src = (const float4*)(aev_ws + (size_t)(c * A_ + a) * FAEV);
                dst[l] = src[l];
                if (l < 32) dst[l + 64] = src[l + 64];
            } else {
                dst[l] = make_float4(0.f, 0.f, 0.f, 0.f);
                if (l < 32) dst[l + 64] = make_float4(0.f, 0.f, 0.f, 0.f);
            }
        }
        __syncthreads();

        // ---- layer 1: 384 -> 160 ----
        if (t < 160) {
            float acc0 = 0.f, acc1 = 0.f, acc2 = 0.f, acc3 = 0.f;
            for (int f = 0; f < FAEV; f += 4) {
                float w0 = W1s[(f + 0) * 160 + t];
                float w1 = W1s[(f + 1) * 160 + t];
                float w2 = W1s[(f + 2) * 160 + t];
                float w3 = W1s[(f + 3) * 160 + t];
                float4 a0 = *(const float4*)&aev_s[0][f];
                float4 a1 = *(const float4*)&aev_s[1][f];
                float4 a2 = *(const float4*)&aev_s[2][f];
                float4 a3 = *(const float4*)&aev_s[3][f];
                acc0 += a0.x * w0 + a0.y * w1 + a0.z * w2 + a0.w * w3;
                acc1 += a1.x * w0 + a1.y * w1 + a1.z * w2 + a1.w * w3;
                acc2 += a2.x * w0 + a2.y * w1 + a2.z * w2 + a2.w * w3;
                acc3 += a3.x * w0 + a3.y * w1 + a3.z * w2 + a3.w * w3;
            }
            float bb = b1s[t];
            float x;
            x = acc0 + bb; h1_s[0][t] = (x > 0.f) ? x : 0.1f * (__expf(10.f * x) - 1.f);
            x = acc1 + bb; h1_s[1][t] = (x > 0.f) ? x : 0.1f * (__expf(10.f * x) - 1.f);
            x = acc2 + bb; h1_s[2][t] = (x > 0.f) ? x : 0.1f * (__expf(10.f * x) - 1.f);
            x = acc3 + bb; h1_s[3][t] = (x > 0.f) ? x : 0.1f * (__expf(10.f * x) - 1.f);
        }
        __syncthreads();   // aev_s dead -> reuse as h2/h3

        // ---- layer 2: 160 -> 128 ----
        if (t < 128) {
            float acc0 = 0.f, acc1 = 0.f, acc2 = 0.f, acc3 = 0.f;
            for (int f = 0; f < 160; f += 4) {
                float w0 = W2s[(f + 0) * 128 + t];
                float w1 = W2s[(f + 1) * 128 + t];
                float w2 = W2s[(f + 2) * 128 + t];
                float w3 = W2s[(f + 3) * 128 + t];
                float4 a0 = *(const float4*)&h1_s[0][f];
                float4 a1 = *(const float4*)&h1_s[1][f];
                float4 a2 = *(const float4*)&h1_s[2][f];
                float4 a3 = *(const float4*)&h1_s[3][f];
                acc0 += a0.x * w0 + a0.y * w1 + a0.z * w2 + a0.w * w3;
                acc1 += a1.x * w0 + a1.y * w1 + a1.z * w2 + a1.w * w3;
                acc2 += a2.x * w0 + a2.y * w1 + a2.z * w2 + a2.w * w3;
                acc3 += a3.x * w0 + a3.y * w1 + a3.z * w2 + a3.w * w3;
            }
            float bb = b2s[t];
            float x;
            x = acc0 + bb; h2_s[0][t] = (x > 0.f) ? x : 0.1f * (__expf(10.f * x) - 1.f);
            x = acc1 + bb; h2_s[1][t] = (x > 0.f) ? x : 0.1f * (__expf(10.f * x) - 1.f);
            x = acc2 + bb; h2_s[2][t] = (x > 0.f) ? x : 0.1f * (__expf(10.f * x) - 1.f);
            x = acc3 + bb; h2_s[3][t] = (x > 0.f) ? x : 0.1f * (__expf(10.f * x) - 1.f);
        }
        __syncthreads();

        // ---- layer 3: 128 -> 96 ----
        if (t < 96) {
            float acc0 = 0.f, acc1 = 0.f, acc2 = 0.f, acc3 = 0.f;
            for (int f = 0; f < 128; f += 4) {
                float w0 = W3s[(f + 0) * 96 + t];
                float w1 = W3s[(f + 1) * 96 + t];
                float w2 = W3s[(f + 2) * 96 + t];
                float w3 = W3s[(f + 3) * 96 + t];
                float4 a0 = *(const float4*)&h2_s[0][f];
                float4 a1 = *(const float4*)&h2_s[1][f];
                float4 a2 = *(const float4*)&h2_s[2][f];
                float4 a3 = *(const float4*)&h2_s[3][f];
                acc0 += a0.x * w0 + a0.y * w1 + a0.z * w2 + a0.w * w3;
                acc1 += a1.x * w0 + a1.y * w1 + a1.z * w2 + a1.w * w3;
                acc2 += a2.x * w0 + a2.y * w1 + a2.z * w2 + a2.w * w3;
                acc3 += a3.x * w0 + a3.y * w1 + a3.z * w2 + a3.w * w3;
            }
            float bb = b3s[t];
            float x;
            x = acc0 + bb; h3_s[0][t] = (x > 0.f) ? x : 0.1f * (__expf(10.f * x) - 1.f);
            x = acc1 + bb; h3_s[1][t] = (x > 0.f) ? x : 0.1f * (__expf(10.f * x) - 1.f);
            x = acc2 + bb; h3_s[2][t] = (x > 0.f) ? x : 0.1f * (__expf(10.f * x) - 1.f);
            x = acc3 + bb; h3_s[3][t] = (x > 0.f) ? x : 0.1f * (__expf(10.f * x) - 1.f);
        }
        __syncthreads();

        // ---- layer 4: 96 -> 1, 32-lane parallel dot + shuffle reduce ----
        if (t < 128) {
            int m = t >> 5, l = t & 31;
            if (m < matoms) {
                float p = h3_s[m][l]      * W4s[l]
                        + h3_s[m][l + 32] * W4s[l + 32]
                        + h3_s[m][l + 64] * W4s[l + 64];
                #pragma unroll
                for (int off = 16; off >= 1; off >>= 1)
                    p += __shfl_xor(p, off, 32);
                if (l == 0) atomicAdd(&out[c], p + bb4);
            }
        }
        __syncthreads();   // protect LDS before next tile (rare second iteration)
    }
}

extern "C" void kernel_launch(void* const* d_in, const int* in_sizes, int n_in,
                              void* d_out, int out_size, void* d_ws, size_t ws_size,
                              hipStream_t stream) {
    const int*   element_idxs  = (const int*)d_in[0];
    const int*   neighbor_idxs = (const int*)d_in[1];
    const float* distances     = (const float*)d_in[2];
    const float* diff_vectors  = (const float*)d_in[3];
    const float* W1 = (const float*)d_in[4];
    const float* b1 = (const float*)d_in[5];
    const float* W2 = (const float*)d_in[6];
    const float* b2 = (const float*)d_in[7];
    const float* W3 = (const float*)d_in[8];
    const float* b3 = (const float*)d_in[9];
    const float* W4 = (const float*)d_in[10];
    const float* b4 = (const float*)d_in[11];
    float* out = (float*)d_out;

    // workspace layout
    float* aev_ws  = (float*)d_ws;                                       // 8192*384 f32 = 12.58 MB
    int*   mol_cnt = (int*)((char*)d_ws + (size_t)NATOM * FAEV * 4);     // 128*4 ints
    int*   mol_lst = mol_cnt + C_ * S_;                                  // 128*4*64 ints

    hipLaunchKernelGGL(aev_kernel, dim3(NATOM / 4), dim3(256), 0, stream,
                       element_idxs, neighbor_idxs, distances, diff_vectors,
                       aev_ws, mol_cnt, mol_lst, out);
    hipLaunchKernelGGL(mlp_kernel, dim3(C_ * S_ * 6), dim3(256), 0, stream,
                       aev_ws, mol_cnt, mol_lst,
                       W1, b1, W2, b2, W3, b3, W4, b4, out);
}